// Round 2
// baseline (1036.093 us; speedup 1.0000x reference)
//
#include <hip/hip_runtime.h>
#include <hip/hip_bf16.h>

// ---- problem constants ----
#define BATCH 4
#define SEQ   2048
#define DIN   4096
#define DOUT  4096
#define MTOT  (BATCH * SEQ)     // 8192
#define RANK  16

typedef __bf16 bf8_t  __attribute__((ext_vector_type(8)));
typedef float  f4_t   __attribute__((ext_vector_type(4)));

#define GLD_LDS(g, l) \
  __builtin_amdgcn_global_load_lds((const __attribute__((address_space(1))) void*)(g), \
                                   (__attribute__((address_space(3))) void*)(l), 16, 0, 0)

// ---------------------------------------------------------------------------
// Kernel 1: lowS[m][r] = scale[b(m)] * sum_k x[m][k] * A[b(m)][r][k]   (fp32)
// One block = 2 rows. 256 threads, 16 k's per thread (f32 inputs).
// ---------------------------------------------------------------------------
__global__ __launch_bounds__(256) void lora_low_kernel(
    const float* __restrict__ x, const float* __restrict__ Aw,
    const float* __restrict__ scales, const int* __restrict__ adapter_id,
    float* __restrict__ lowS) {
  const int t  = threadIdx.x;
  const int m0 = blockIdx.x * 2;
  const int b  = adapter_id[m0 >> 11];           // m0 / 2048
  const float scale = scales[b];

  const float* xp = x + (size_t)m0 * DIN + t * 16;
  float x0[16], x1[16];
#pragma unroll
  for (int c = 0; c < 4; ++c) {
    f4_t v0 = *(const f4_t*)(xp + c * 4);
    f4_t v1 = *(const f4_t*)(xp + DIN + c * 4);
#pragma unroll
    for (int j = 0; j < 4; ++j) { x0[c * 4 + j] = v0[j]; x1[c * 4 + j] = v1[j]; }
  }

  const float* ap = Aw + (size_t)b * RANK * DIN + t * 16;
  float acc0[RANK], acc1[RANK];
#pragma unroll
  for (int r = 0; r < RANK; ++r) {
    float s0 = 0.f, s1 = 0.f;
#pragma unroll
    for (int c = 0; c < 4; ++c) {
      f4_t a = *(const f4_t*)(ap + (size_t)r * DIN + c * 4);
#pragma unroll
      for (int j = 0; j < 4; ++j) {
        s0 += x0[c * 4 + j] * a[j];
        s1 += x1[c * 4 + j] * a[j];
      }
    }
    acc0[r] = s0; acc1[r] = s1;
  }

  // wave butterfly reduce (64 lanes)
#pragma unroll
  for (int r = 0; r < RANK; ++r) {
#pragma unroll
    for (int off = 32; off > 0; off >>= 1) {
      acc0[r] += __shfl_down(acc0[r], off);
      acc1[r] += __shfl_down(acc1[r], off);
    }
  }

  __shared__ float red[4][2][RANK];
  const int w = t >> 6, lane = t & 63;
  if (lane == 0) {
#pragma unroll
    for (int r = 0; r < RANK; ++r) { red[w][0][r] = acc0[r]; red[w][1][r] = acc1[r]; }
  }
  __syncthreads();
  if (t < 32) {
    const int row = t >> 4, r = t & 15;
    float s = red[0][row][r] + red[1][row][r] + red[2][row][r] + red[3][row][r];
    lowS[(size_t)(m0 + row) * RANK + r] = s * scale;
  }
}

// ---------------------------------------------------------------------------
// Kernel 2: out = x @ W^T + bias + lowS @ loraB[b]^T    (f32 in, f32 out)
// 128x128 tile, BK=32 f32. Stage f32 via global_load_lds (XOR k-chunk swizzle
// to kill bank conflicts), convert to bf16 at frag-read, 16x16x32 bf16 MFMA.
// LoRA fused as one zero-padded MFMA k-step in the epilogue.
// ---------------------------------------------------------------------------
#define TM 128
#define TN 128
#define BK 32

__global__ __launch_bounds__(256) void lora_gemm_kernel(
    const float* __restrict__ x, const float* __restrict__ wgt,
    const float* __restrict__ bias, const float* __restrict__ loraB,
    const int* __restrict__ adapter_id, const float* __restrict__ lowS,
    float* __restrict__ out) {
  __shared__ float As[TM * BK];   // 16 KB
  __shared__ float Bs[TN * BK];   // 16 KB

  const int t    = threadIdx.x;
  const int w    = t >> 6;
  const int lane = t & 63;
  const int quad = lane >> 4;
  const int l16  = lane & 15;
  const int m0 = blockIdx.y * TM;
  const int n0 = blockIdx.x * TN;
  const int wave_m = (w & 1) * 64;
  const int wave_n = (w >> 1) * 64;

  f4_t acc[4][4];
#pragma unroll
  for (int i = 0; i < 4; ++i)
#pragma unroll
    for (int j = 0; j < 4; ++j) acc[i][j] = (f4_t)0.f;

  // ---- staging setup ----
  // Round r (r=0..3): 256 threads cover 32 rows x 32 floats. Thread t -> row
  // r*32 + (t>>3), swizzled chunk ((t&7) ^ ((t>>3)&7)) of 4 floats. LDS dest is
  // wave-uniform base + lane*16B (global_load_lds requirement).
  const int srow   = t >> 3;                    // 0..31
  const int schunk = (t & 7) ^ (srow & 7);      // XOR swizzle
  const float* gA[4]; const float* gB[4];
  float* lA[4]; float* lB[4];
#pragma unroll
  for (int r = 0; r < 4; ++r) {
    gA[r] = x   + (size_t)(m0 + r * 32 + srow) * DIN + schunk * 4;
    gB[r] = wgt + (size_t)(n0 + r * 32 + srow) * DIN + schunk * 4;
    lA[r] = &As[r * 1024 + w * 256];
    lB[r] = &Bs[r * 1024 + w * 256];
  }

  // frag-read swizzled chunk offsets (per-thread constants)
  const int sw = l16 & 7;
  const int c0 = ((2 * quad)     ^ sw) * 4;   // floats k = quad*8 .. +3
  const int c1 = ((2 * quad + 1) ^ sw) * 4;   // floats k = quad*8+4 .. +7

  for (int k0 = 0; k0 < DIN; k0 += BK) {
#pragma unroll
    for (int r = 0; r < 4; ++r) GLD_LDS(gA[r] + k0, lA[r]);
#pragma unroll
    for (int r = 0; r < 4; ++r) GLD_LDS(gB[r] + k0, lB[r]);
    __syncthreads();   // drains vmcnt -> staged data visible to all

    bf8_t af[4], bfr[4];
#pragma unroll
    for (int i = 0; i < 4; ++i) {
      const float* base = &As[(wave_m + i * 16 + l16) * BK];
      f4_t u0 = *(const f4_t*)(base + c0);
      f4_t u1 = *(const f4_t*)(base + c1);
#pragma unroll
      for (int e = 0; e < 4; ++e) { af[i][e] = (__bf16)u0[e]; af[i][4 + e] = (__bf16)u1[e]; }
    }
#pragma unroll
    for (int j = 0; j < 4; ++j) {
      const float* base = &Bs[(wave_n + j * 16 + l16) * BK];
      f4_t u0 = *(const f4_t*)(base + c0);
      f4_t u1 = *(const f4_t*)(base + c1);
#pragma unroll
      for (int e = 0; e < 4; ++e) { bfr[j][e] = (__bf16)u0[e]; bfr[j][4 + e] = (__bf16)u1[e]; }
    }
#pragma unroll
    for (int i = 0; i < 4; ++i)
#pragma unroll
      for (int j = 0; j < 4; ++j)
        acc[i][j] = __builtin_amdgcn_mfma_f32_16x16x32_bf16(af[i], bfr[j], acc[i][j], 0, 0, 0);

    __syncthreads();   // protect LDS from next iteration's staging
  }

  // ---- LoRA epilogue: one zero-padded MFMA k-step (k=0..15 valid) ----
  const int b = adapter_id[m0 >> 11];
  bf8_t alow[4], blow[4];
  if (quad < 2) {
#pragma unroll
    for (int i = 0; i < 4; ++i) {
      const float* p = &lowS[(size_t)(m0 + wave_m + i * 16 + l16) * RANK + quad * 8];
      f4_t u0 = *(const f4_t*)p;
      f4_t u1 = *(const f4_t*)(p + 4);
#pragma unroll
      for (int e = 0; e < 4; ++e) { alow[i][e] = (__bf16)u0[e]; alow[i][4 + e] = (__bf16)u1[e]; }
    }
#pragma unroll
    for (int j = 0; j < 4; ++j) {
      const float* p = &loraB[((size_t)b * DOUT + n0 + wave_n + j * 16 + l16) * RANK + quad * 8];
      f4_t u0 = *(const f4_t*)p;
      f4_t u1 = *(const f4_t*)(p + 4);
#pragma unroll
      for (int e = 0; e < 4; ++e) { blow[j][e] = (__bf16)u0[e]; blow[j][4 + e] = (__bf16)u1[e]; }
    }
  } else {
#pragma unroll
    for (int i = 0; i < 4; ++i)
#pragma unroll
      for (int e = 0; e < 8; ++e) { alow[i][e] = (__bf16)0.f; blow[i][e] = (__bf16)0.f; }
  }
#pragma unroll
  for (int i = 0; i < 4; ++i)
#pragma unroll
    for (int j = 0; j < 4; ++j)
      acc[i][j] = __builtin_amdgcn_mfma_f32_16x16x32_bf16(alow[i], blow[j], acc[i][j], 0, 0, 0);

  // ---- bias + store (C/D layout: col = lane&15, row = quad*4 + reg) ----
#pragma unroll
  for (int j = 0; j < 4; ++j) {
    const int c = n0 + wave_n + j * 16 + l16;
    const float bc = bias[c];
#pragma unroll
    for (int i = 0; i < 4; ++i) {
      const int r0 = m0 + wave_m + i * 16 + quad * 4;
#pragma unroll
      for (int e = 0; e < 4; ++e)
        out[(size_t)(r0 + e) * DOUT + c] = acc[i][j][e] + bc;
    }
  }
}

extern "C" void kernel_launch(void* const* d_in, const int* in_sizes, int n_in,
                              void* d_out, int out_size, void* d_ws, size_t ws_size,
                              hipStream_t stream) {
  const float* x       = (const float*)d_in[0];
  const float* weight  = (const float*)d_in[1];
  const float* bias    = (const float*)d_in[2];
  const float* lora_a  = (const float*)d_in[3];
  const float* lora_b  = (const float*)d_in[4];
  const float* scaling = (const float*)d_in[5];
  const int*   adapter = (const int*)d_in[6];
  float* out  = (float*)d_out;
  float* lowS = (float*)d_ws;   // MTOT * RANK fp32 = 512 KB

  lora_low_kernel<<<MTOT / 2, 256, 0, stream>>>(x, lora_a, scaling, adapter, lowS);
  dim3 grid(DOUT / TN, MTOT / TM);
  lora_gemm_kernel<<<grid, 256, 0, stream>>>(x, weight, bias, lora_b, adapter, lowS, out);
}

// Round 3
// 671.002 us; speedup vs baseline: 1.5441x; 1.5441x over previous
//
#include <hip/hip_runtime.h>
#include <hip/hip_bf16.h>

// ---- problem constants ----
#define BATCH 4
#define SEQ   2048
#define DIN   4096
#define DOUT  4096
#define MTOT  (BATCH * SEQ)     // 8192
#define RANK  16

typedef __bf16 bf8_t  __attribute__((ext_vector_type(8)));
typedef float  f4_t   __attribute__((ext_vector_type(4)));

#define GLD_LDS(g, l) \
  __builtin_amdgcn_global_load_lds((const __attribute__((address_space(1))) void*)(g), \
                                   (__attribute__((address_space(3))) void*)(l), 16, 0, 0)

// ---------------------------------------------------------------------------
// Kernel A: convert weight f32 -> bf16 (grid-stride-free exact cover, 8/thread)
// ---------------------------------------------------------------------------
__global__ __launch_bounds__(256) void conv_w_kernel(
    const float* __restrict__ w, __bf16* __restrict__ wb) {
  const size_t i = ((size_t)blockIdx.x * 256 + threadIdx.x) * 8;
  f4_t a = *(const f4_t*)(w + i);
  f4_t b = *(const f4_t*)(w + i + 4);
  bf8_t o;
#pragma unroll
  for (int e = 0; e < 4; ++e) { o[e] = (__bf16)a[e]; o[4 + e] = (__bf16)b[e]; }
  *(bf8_t*)(wb + i) = o;
}

// ---------------------------------------------------------------------------
// Kernel B: lowS[m][r] += scale * sum_k x[m][k]*A[b][r][k]  (MFMA, k-split=8)
// Also emits x_bf16 (fused conversion: we're reading all of x anyway).
// Block = 256 thr = 4 waves; wave owns 16 rows x 512 k. grid = (128, 8).
// A-frag = x rows (cvt bf16), B-frag = 16 adapter rows (cvt bf16).
// lowS must be zeroed before launch (hipMemsetAsync).
// ---------------------------------------------------------------------------
__global__ __launch_bounds__(256) void lora_low_kernel(
    const float* __restrict__ x, const float* __restrict__ Aw,
    const float* __restrict__ scales, const int* __restrict__ adapter_id,
    __bf16* __restrict__ xb, float* __restrict__ lowS) {
  const int t    = threadIdx.x;
  const int w    = t >> 6;
  const int lane = t & 63;
  const int quad = lane >> 4;
  const int l16  = lane & 15;
  const int m0   = blockIdx.x * 64;
  const int kb   = blockIdx.y * 512;
  const int b    = adapter_id[m0 >> 11];
  const float scale = scales[b];

  const int row = m0 + w * 16 + l16;
  const float*  xp  = x  + (size_t)row * DIN + kb + quad * 8;
  __bf16*       xbp = xb + (size_t)row * DIN + kb + quad * 8;
  const float*  ap  = Aw + ((size_t)b * RANK + l16) * DIN + kb + quad * 8;

  f4_t acc = (f4_t)0.f;
#pragma unroll 4
  for (int it = 0; it < 16; ++it) {
    const int off = it * 32;
    f4_t u0 = *(const f4_t*)(xp + off);
    f4_t u1 = *(const f4_t*)(xp + off + 4);
    f4_t v0 = *(const f4_t*)(ap + off);
    f4_t v1 = *(const f4_t*)(ap + off + 4);
    bf8_t af, bfr;
#pragma unroll
    for (int e = 0; e < 4; ++e) {
      af[e] = (__bf16)u0[e]; af[4 + e] = (__bf16)u1[e];
      bfr[e] = (__bf16)v0[e]; bfr[4 + e] = (__bf16)v1[e];
    }
    *(bf8_t*)(xbp + off) = af;   // fused x f32->bf16 emission
    acc = __builtin_amdgcn_mfma_f32_16x16x32_bf16(af, bfr, acc, 0, 0, 0);
  }

  // C/D: col(rank) = l16, row = quad*4 + e.  Partial over k-split -> atomicAdd.
#pragma unroll
  for (int e = 0; e < 4; ++e)
    atomicAdd(&lowS[(size_t)(m0 + w * 16 + quad * 4 + e) * RANK + l16], acc[e] * scale);
}

// ---------------------------------------------------------------------------
// Kernel C: out = x @ W^T + bias + lowS @ loraB[b]^T   (bf16 GEMM, f32 out)
// m97 structure: 128x128 tile, BK=32 bf16, global_load_lds width-16, 4 waves
// x 4x4 subtiles of 16x16x32 MFMA. Chunk-XOR swizzle (chunk ^= row&3) cuts
// frag-read bank conflicts to 2-way (free). LoRA = one zero-padded MFMA.
// ---------------------------------------------------------------------------
#define TM 128
#define TN 128
#define BK 32

__global__ __launch_bounds__(256) void lora_gemm_kernel(
    const __bf16* __restrict__ x, const __bf16* __restrict__ wgt,
    const float* __restrict__ bias, const float* __restrict__ loraB,
    const int* __restrict__ adapter_id, const float* __restrict__ lowS,
    float* __restrict__ out) {
  __shared__ __bf16 As[TM * BK];   // 8 KB
  __shared__ __bf16 Bs[TN * BK];   // 8 KB

  const int t    = threadIdx.x;
  const int w    = t >> 6;
  const int lane = t & 63;
  const int quad = lane >> 4;
  const int l16  = lane & 15;
  const int m0 = blockIdx.y * TM;
  const int n0 = blockIdx.x * TN;
  const int wave_m = (w & 1) * 64;
  const int wave_n = (w >> 1) * 64;

  f4_t acc[4][4];
#pragma unroll
  for (int i = 0; i < 4; ++i)
#pragma unroll
    for (int j = 0; j < 4; ++j) acc[i][j] = (f4_t)0.f;

  // staging: round r covers rows r*64 + (t>>2); chunk-position (t&3) of row rr
  // holds global chunk (t&3)^(rr&3)  (8 bf16 = 16 B chunks, 4 per row)
  const int srow   = t >> 2;                    // 0..63
  const int schunk = (t & 3) ^ (srow & 3);      // XOR swizzle
  const __bf16* gA0 = x   + (size_t)(m0 + srow) * DIN + schunk * 8;
  const __bf16* gA1 = x   + (size_t)(m0 + 64 + srow) * DIN + schunk * 8;
  const __bf16* gB0 = wgt + (size_t)(n0 + srow) * DIN + schunk * 8;
  const __bf16* gB1 = wgt + (size_t)(n0 + 64 + srow) * DIN + schunk * 8;
  __bf16* lA0 = &As[w * 512];          // wave-uniform LDS bases (+lane*16B in HW)
  __bf16* lA1 = &As[2048 + w * 512];
  __bf16* lB0 = &Bs[w * 512];
  __bf16* lB1 = &Bs[2048 + w * 512];

  // frag-read chunk (per-thread constant): want global chunk `quad` at rows
  // with row&3 == l16&3  ->  LDS chunk = quad ^ (l16&3)
  const int fc = (quad ^ (l16 & 3)) * 8;

  for (int k0 = 0; k0 < DIN; k0 += BK) {
    GLD_LDS(gA0 + k0, lA0);
    GLD_LDS(gA1 + k0, lA1);
    GLD_LDS(gB0 + k0, lB0);
    GLD_LDS(gB1 + k0, lB1);
    __syncthreads();   // drains vmcnt -> staged data visible

    bf8_t af[4], bfr[4];
#pragma unroll
    for (int i = 0; i < 4; ++i)
      af[i] = *(const bf8_t*)&As[(wave_m + i * 16 + l16) * BK + fc];
#pragma unroll
    for (int j = 0; j < 4; ++j)
      bfr[j] = *(const bf8_t*)&Bs[(wave_n + j * 16 + l16) * BK + fc];
#pragma unroll
    for (int i = 0; i < 4; ++i)
#pragma unroll
      for (int j = 0; j < 4; ++j)
        acc[i][j] = __builtin_amdgcn_mfma_f32_16x16x32_bf16(af[i], bfr[j], acc[i][j], 0, 0, 0);

    __syncthreads();   // protect LDS from next iteration's staging
  }

  // ---- LoRA epilogue: one zero-padded MFMA k-step (k=0..15 valid) ----
  const int b = adapter_id[m0 >> 11];
  bf8_t alow[4], blow[4];
  if (quad < 2) {
#pragma unroll
    for (int i = 0; i < 4; ++i) {
      const float* p = &lowS[(size_t)(m0 + wave_m + i * 16 + l16) * RANK + quad * 8];
      f4_t u0 = *(const f4_t*)p;
      f4_t u1 = *(const f4_t*)(p + 4);
#pragma unroll
      for (int e = 0; e < 4; ++e) { alow[i][e] = (__bf16)u0[e]; alow[i][4 + e] = (__bf16)u1[e]; }
    }
#pragma unroll
    for (int j = 0; j < 4; ++j) {
      const float* p = &loraB[((size_t)b * DOUT + n0 + wave_n + j * 16 + l16) * RANK + quad * 8];
      f4_t u0 = *(const f4_t*)p;
      f4_t u1 = *(const f4_t*)(p + 4);
#pragma unroll
      for (int e = 0; e < 4; ++e) { blow[j][e] = (__bf16)u0[e]; blow[j][4 + e] = (__bf16)u1[e]; }
    }
  } else {
#pragma unroll
    for (int i = 0; i < 4; ++i)
#pragma unroll
      for (int e = 0; e < 8; ++e) { alow[i][e] = (__bf16)0.f; blow[i][e] = (__bf16)0.f; }
  }
#pragma unroll
  for (int i = 0; i < 4; ++i)
#pragma unroll
    for (int j = 0; j < 4; ++j)
      acc[i][j] = __builtin_amdgcn_mfma_f32_16x16x32_bf16(alow[i], blow[j], acc[i][j], 0, 0, 0);

  // ---- bias + store (C/D layout: col = lane&15, row = quad*4 + reg) ----
#pragma unroll
  for (int j = 0; j < 4; ++j) {
    const int c = n0 + wave_n + j * 16 + l16;
    const float bc = bias[c];
#pragma unroll
    for (int i = 0; i < 4; ++i) {
      const int r0 = m0 + wave_m + i * 16 + quad * 4;
#pragma unroll
      for (int e = 0; e < 4; ++e)
        out[(size_t)(r0 + e) * DOUT + c] = acc[i][j][e] + bc;
    }
  }
}

extern "C" void kernel_launch(void* const* d_in, const int* in_sizes, int n_in,
                              void* d_out, int out_size, void* d_ws, size_t ws_size,
                              hipStream_t stream) {
  const float* x       = (const float*)d_in[0];
  const float* weight  = (const float*)d_in[1];
  const float* bias    = (const float*)d_in[2];
  const float* lora_a  = (const float*)d_in[3];
  const float* lora_b  = (const float*)d_in[4];
  const float* scaling = (const float*)d_in[5];
  const int*   adapter = (const int*)d_in[6];
  float* out = (float*)d_out;

  // workspace layout: x_bf16 (64 MiB) | W_bf16 (32 MiB) | lowS (512 KiB)
  __bf16* xb   = (__bf16*)d_ws;
  __bf16* wb   = xb + (size_t)MTOT * DIN;
  float*  lowS = (float*)(wb + (size_t)DOUT * DIN);

  hipMemsetAsync(lowS, 0, (size_t)MTOT * RANK * sizeof(float), stream);
  conv_w_kernel<<<(size_t)DOUT * DIN / 8 / 256, 256, 0, stream>>>(weight, wb);
  dim3 lgrid(MTOT / 64, 8);
  lora_low_kernel<<<lgrid, 256, 0, stream>>>(x, lora_a, scaling, adapter, xb, lowS);
  dim3 grid(DOUT / TN, MTOT / TM);
  lora_gemm_kernel<<<grid, 256, 0, stream>>>(xb, wb, bias, lora_b, adapter, lowS, out);
}